// Round 3
// baseline (1173.979 us; speedup 1.0000x reference)
//
#include <hip/hip_runtime.h>
#include <hip/hip_bf16.h>
#include <stdint.h>
#include <stddef.h>

// Problem constants (from reference): T=2048, B=16, D=1024. ALL I/O = float32.
#define T_DIM 2048
#define B_DIM 16
#define D_DIM 1024
#define BD    (B_DIM * D_DIM)          // 16384 state elements
#define TBD   ((size_t)T_DIM * BD)     // 33554432

using bf16 = __hip_bfloat16;
typedef __attribute__((ext_vector_type(8))) short short8;   // 8 x bf16 = 4 VGPRs
typedef __attribute__((ext_vector_type(4))) float f32x4;

// f32 -> bf16 bits, round-to-nearest-even (finite inputs).
__device__ __forceinline__ unsigned f2bf(float f) {
    unsigned u = __float_as_uint(f);
    return (u + 0x7FFFu + ((u >> 16) & 1u)) >> 16;
}

// ---------------------------------------------------------------------------
// f32 buffer -> bf16 buffer (for MFMA operands). 8 elems/thread.
// ---------------------------------------------------------------------------
__global__ __launch_bounds__(256) void cvt_f32_bf16(
    const float* __restrict__ src, short* __restrict__ dst, int n8)
{
    int i = blockIdx.x * 256 + threadIdx.x;
    if (i >= n8) return;
    const float* p = src + (size_t)i * 8;
    f32x4 a = *(const f32x4*)p;
    f32x4 b = *(const f32x4*)(p + 4);
    short8 r;
    r[0] = (short)f2bf(a[0]); r[1] = (short)f2bf(a[1]);
    r[2] = (short)f2bf(a[2]); r[3] = (short)f2bf(a[3]);
    r[4] = (short)f2bf(b[0]); r[5] = (short)f2bf(b[1]);
    r[6] = (short)f2bf(b[2]); r[7] = (short)f2bf(b[3]);
    *(short8*)(dst + (size_t)i * 8) = r;
}

// ---------------------------------------------------------------------------
// Fused K/V projection GEMM, bf16 operands from ws, f32 bias/output.
//   pre[m][n] = sum_d x[m][d]*W[n][d]  (NT, both row-major K-fast)
//   z==0: k = sigmoid(pre+b_k); z==1: v = tanh(pre+b_v)
// 128x128/block, 4 waves 2x2, mfma_f32_16x16x32_bf16, fragments direct from
// global (A: m=lane&15, k=(lane>>4)*8+j; C/D: col=lane&15,row=(lane>>4)*4+r).
// ---------------------------------------------------------------------------
__global__ __launch_bounds__(256) void gemm_kv_bf16(
    const short* __restrict__ xb,
    const short* __restrict__ Wkb, const float* __restrict__ bk,
    const short* __restrict__ Wvb, const float* __restrict__ bv,
    float* __restrict__ kout, float* __restrict__ vout)
{
    const int tid  = threadIdx.x;
    const int lane = tid & 63;
    const int wave = tid >> 6;
    const int wm   = wave & 1;
    const int wn   = wave >> 1;
    const int quad = lane >> 4;
    const int l15  = lane & 15;

    const int blkn = blockIdx.x;      // 0..7
    const int blkm = blockIdx.y;      // 0..255
    const bool is_k = (blockIdx.z == 0);

    const short* W    = is_k ? Wkb : Wvb;
    const float* bias = is_k ? bk : bv;
    float*       outp = is_k ? kout : vout;

    const int m0 = blkm * 128 + wm * 64;
    const int n0 = blkn * 128 + wn * 64;

    const short* ap = xb + (size_t)(m0 + l15) * D_DIM + quad * 8;
    const short* bp = W  + (size_t)(n0 + l15) * D_DIM + quad * 8;

    f32x4 acc[4][4] = {};

#pragma unroll 2
    for (int ks = 0; ks < D_DIM / 32; ++ks) {
        short8 a[4], b[4];
#pragma unroll
        for (int mt = 0; mt < 4; ++mt)
            a[mt] = *(const short8*)(ap + (size_t)mt * 16 * D_DIM + ks * 32);
#pragma unroll
        for (int nt = 0; nt < 4; ++nt)
            b[nt] = *(const short8*)(bp + (size_t)nt * 16 * D_DIM + ks * 32);
#pragma unroll
        for (int mt = 0; mt < 4; ++mt)
#pragma unroll
            for (int nt = 0; nt < 4; ++nt)
                acc[mt][nt] = __builtin_amdgcn_mfma_f32_16x16x32_bf16(
                    a[mt], b[nt], acc[mt][nt], 0, 0, 0);
    }

    const int gm0 = blkm * 128 + wm * 64 + quad * 4;
    const int gn  = blkn * 128 + wn * 64 + l15;
#pragma unroll
    for (int nt = 0; nt < 4; ++nt) {
        const int n = gn + nt * 16;
        const float bs = bias[n];
#pragma unroll
        for (int mt = 0; mt < 4; ++mt) {
            const int m = gm0 + mt * 16;
#pragma unroll
            for (int r = 0; r < 4; ++r) {
                float pre = acc[mt][nt][r] + bs;
                pre = fminf(20.f, fmaxf(-20.f, pre));
                float o;
                if (is_k) o = 1.f / (1.f + __expf(-pre));                // sigmoid
                else      o = 2.f / (1.f + __expf(-2.f * pre)) - 1.f;    // tanh
                outp[(size_t)(m + r) * D_DIM + n] = o;
            }
        }
    }
}

// ---------------------------------------------------------------------------
// Fallback GEMM when ws too small: load f32 operands, convert in-kernel.
// ---------------------------------------------------------------------------
__device__ __forceinline__ short8 load_cvt8(const float* p) {
    f32x4 a = *(const f32x4*)p;
    f32x4 b = *(const f32x4*)(p + 4);
    short8 r;
    r[0] = (short)f2bf(a[0]); r[1] = (short)f2bf(a[1]);
    r[2] = (short)f2bf(a[2]); r[3] = (short)f2bf(a[3]);
    r[4] = (short)f2bf(b[0]); r[5] = (short)f2bf(b[1]);
    r[6] = (short)f2bf(b[2]); r[7] = (short)f2bf(b[3]);
    return r;
}

__global__ __launch_bounds__(256) void gemm_kv_f32src(
    const float* __restrict__ x,
    const float* __restrict__ Wk, const float* __restrict__ bk,
    const float* __restrict__ Wv, const float* __restrict__ bv,
    float* __restrict__ kout, float* __restrict__ vout)
{
    const int tid  = threadIdx.x;
    const int lane = tid & 63;
    const int wave = tid >> 6;
    const int wm   = wave & 1;
    const int wn   = wave >> 1;
    const int quad = lane >> 4;
    const int l15  = lane & 15;

    const int blkn = blockIdx.x;
    const int blkm = blockIdx.y;
    const bool is_k = (blockIdx.z == 0);

    const float* W    = is_k ? Wk : Wv;
    const float* bias = is_k ? bk : bv;
    float*       outp = is_k ? kout : vout;

    const int m0 = blkm * 128 + wm * 64;
    const int n0 = blkn * 128 + wn * 64;

    const float* ap = x + (size_t)(m0 + l15) * D_DIM + quad * 8;
    const float* bp = W + (size_t)(n0 + l15) * D_DIM + quad * 8;

    f32x4 acc[4][4] = {};

    for (int ks = 0; ks < D_DIM / 32; ++ks) {
        short8 a[4], b[4];
#pragma unroll
        for (int mt = 0; mt < 4; ++mt)
            a[mt] = load_cvt8(ap + (size_t)mt * 16 * D_DIM + ks * 32);
#pragma unroll
        for (int nt = 0; nt < 4; ++nt)
            b[nt] = load_cvt8(bp + (size_t)nt * 16 * D_DIM + ks * 32);
#pragma unroll
        for (int mt = 0; mt < 4; ++mt)
#pragma unroll
            for (int nt = 0; nt < 4; ++nt)
                acc[mt][nt] = __builtin_amdgcn_mfma_f32_16x16x32_bf16(
                    a[mt], b[nt], acc[mt][nt], 0, 0, 0);
    }

    const int gm0 = blkm * 128 + wm * 64 + quad * 4;
    const int gn  = blkn * 128 + wn * 64 + l15;
#pragma unroll
    for (int nt = 0; nt < 4; ++nt) {
        const int n = gn + nt * 16;
        const float bs = bias[n];
#pragma unroll
        for (int mt = 0; mt < 4; ++mt) {
            const int m = gm0 + mt * 16;
#pragma unroll
            for (int r = 0; r < 4; ++r) {
                float pre = acc[mt][nt][r] + bs;
                pre = fminf(20.f, fmaxf(-20.f, pre));
                float o;
                if (is_k) o = 1.f / (1.f + __expf(-pre));
                else      o = 2.f / (1.f + __expf(-2.f * pre)) - 1.f;
                outp[(size_t)(m + r) * D_DIM + n] = o;
            }
        }
    }
}

// ---------------------------------------------------------------------------
// Sequential scan over T, f32 I/O. One thread per (b,d) chain.
//   h_t = (1-k_t) h_{t-1} + k_t v_t ;  out_t = h_t^2 * sigmoid(h_t)
// kw aliases outp and vw aliases hsec+BD (element-exact in place): every slot
// is loaded by its owning thread strictly before that same thread stores it
// (store value data-depends on the load), so in-place RMW is safe.
// ---------------------------------------------------------------------------
__global__ __launch_bounds__(64) void scan_kernel(
    const float* kw, const float* vw, const float* h0,
    float* outp, float* hsec)
{
    const int c = blockIdx.x * 64 + threadIdx.x;   // 0..16383
    float h = h0[c];
    hsec[c] = h;                                   // h[0] = h0

    const float* kp = kw + c;
    const float* vp = vw + c;
    float* op = outp + c;
    float* hp = hsec + BD + c;

    for (int t = 0; t < T_DIM; t += 8) {
        float kk[8], vv[8];
#pragma unroll
        for (int j = 0; j < 8; ++j) {
            kk[j] = kp[(size_t)(t + j) * BD];
            vv[j] = vp[(size_t)(t + j) * BD];
        }
#pragma unroll
        for (int j = 0; j < 8; ++j) {
            h = (1.f - kk[j]) * h + kk[j] * vv[j];
            hp[(size_t)(t + j) * BD] = h;
            const float sig = 1.f / (1.f + __expf(-h));
            op[(size_t)(t + j) * BD] = h * h * sig;
        }
    }
}

// ---------------------------------------------------------------------------
extern "C" void kernel_launch(void* const* d_in, const int* in_sizes, int n_in,
                              void* d_out, int out_size, void* d_ws, size_t ws_size,
                              hipStream_t stream)
{
    const float* x  = (const float*)d_in[0];   // [T,B,D]
    const float* h0 = (const float*)d_in[1];   // [B,D]
    const float* Wk = (const float*)d_in[2];   // [D,D]
    const float* bk = (const float*)d_in[3];   // [D]
    const float* Wv = (const float*)d_in[4];   // [D,D]
    const float* bv = (const float*)d_in[5];   // [D]

    float* outp = (float*)d_out;               // output section [T,B,D]
    float* hsec = outp + TBD;                  // h section [T+1,B,D]

    // k -> output section, v -> h[1:] section: element-exact in-place (safe,
    // see scan_kernel comment). No workspace needed for k/v.
    float* kw = outp;
    float* vw = hsec + BD;

    const size_t need_bf16 = (TBD + 2 * (size_t)D_DIM * D_DIM) * sizeof(short);
    if (ws_size >= need_bf16) {
        short* xb  = (short*)d_ws;                       // [T*B, D] bf16
        short* Wkb = xb + TBD;                           // [D, D] bf16
        short* Wvb = Wkb + (size_t)D_DIM * D_DIM;
        cvt_f32_bf16<<<dim3((int)(TBD / 8 / 256)), 256, 0, stream>>>(x, xb, (int)(TBD / 8));
        cvt_f32_bf16<<<dim3(D_DIM * D_DIM / 8 / 256), 256, 0, stream>>>(Wk, Wkb, D_DIM * D_DIM / 8);
        cvt_f32_bf16<<<dim3(D_DIM * D_DIM / 8 / 256), 256, 0, stream>>>(Wv, Wvb, D_DIM * D_DIM / 8);
        gemm_kv_bf16<<<dim3(8, 256, 2), 256, 0, stream>>>(xb, Wkb, bk, Wvb, bv, kw, vw);
    } else {
        gemm_kv_f32src<<<dim3(8, 256, 2), 256, 0, stream>>>(x, Wk, bk, Wv, bv, kw, vw);
    }

    scan_kernel<<<dim3(BD / 64), 64, 0, stream>>>(kw, vw, h0, outp, hsec);
}